// Round 12
// baseline (307.909 us; speedup 1.0000x reference)
//
#include <hip/hip_runtime.h>
#include <math.h>

#define NB 8
#define NS 1024
#define NE 1024
#define NH 16
#define ND 64
#define NL 1024

typedef __attribute__((ext_vector_type(8))) short short8;
typedef __attribute__((ext_vector_type(4))) float f32x4;
typedef __attribute__((ext_vector_type(16))) float f32x16;

__device__ __forceinline__ ushort f2bf(float f) {
    union { float f; unsigned u; } v; v.f = f;
    unsigned r = v.u + 0x7fffu + ((v.u >> 16) & 1u);
    return (ushort)(r >> 16);
}
__device__ __forceinline__ float bf2f(ushort u) {
    union { unsigned u; float f; } v; v.u = ((unsigned)u) << 16;
    return v.f;
}

__device__ __forceinline__ void stage16(const ushort* gsrc, ushort* lbase) {
    __builtin_amdgcn_global_load_lds((const __attribute__((address_space(1))) void*)gsrc,
                                     (__attribute__((address_space(3))) void*)lbase,
                                     16, 0, 0);
}

// ---------------- casts ----------------
__global__ __launch_bounds__(256)
void cast_f2b4(const float* __restrict__ in, ushort* __restrict__ out, int n4) {
    int i = blockIdx.x * 256 + threadIdx.x;
    if (i >= n4) return;
    float4 v = ((const float4*)in)[i];
    ((ushort4*)out)[i] = make_ushort4(f2bf(v.x), f2bf(v.y), f2bf(v.z), f2bf(v.w));
}

// all four weights -> consecutive bf16 buffers (Wqb|Wkb|Wvb|Wob)
__global__ __launch_bounds__(256)
void cast_w4(const float* __restrict__ Wq, const float* __restrict__ Wk,
             const float* __restrict__ Wv, const float* __restrict__ Wo,
             ushort* __restrict__ out) {
    int i = blockIdx.x * 256 + threadIdx.x;   // [0, 4*262144)
    const int seg = i >> 18, j = i & 262143;
    const float* src = seg == 0 ? Wq : seg == 1 ? Wk : seg == 2 ? Wv : Wo;
    float4 v = ((const float4*)src)[j];
    ((ushort4*)out)[i] = make_ushort4(f2bf(v.x), f2bf(v.y), f2bf(v.z), f2bf(v.w));
}

__global__ __launch_bounds__(256)
void cast_pek(const float* __restrict__ pek, ushort* __restrict__ out, int n) {
    int i = blockIdx.x * 256 + threadIdx.x;
    if (i < n) out[i] = f2bf(pek[i]);
}

// PEVTs[d][r'] = bf16(PEV[r'+1][d]), r' in [0,1056)
__global__ __launch_bounds__(256)
void cast_pevt(const float* __restrict__ pev, ushort* __restrict__ out) {
    int i = blockIdx.x * 256 + threadIdx.x;
    if (i >= 64 * 1056) return;
    int d = i / 1056, r = i % 1056;
    out[(size_t)d * 1056 + r] = f2bf(pev[(size_t)(r + 1) * ND + d]);
}

// ---------------- MFMA GEMM: C = A @ W^T (bf16 in, fp32 acc) ----------------
// MODE 0: bf16 scatter -> [B,H,S,D]; MODE 1: fp32 row-major;
// MODE 3: operands (Wv, x): m=(h,d), n=(b,s); bf16 -> [B,H,D,S]
template<int MODE>
__global__ __launch_bounds__(256)
void gemm_mfma(const ushort* __restrict__ A, const ushort* __restrict__ W,
               float* __restrict__ Cf, ushort* __restrict__ Cb)
{
    constexpr int K = 1024;
    __shared__ __align__(16) ushort As[128 * 32];
    __shared__ __align__(16) ushort Bs[128 * 32];
    const int tid = threadIdx.x;
    const int w   = tid >> 6;
    const int l   = tid & 63;
    const int m0  = blockIdx.x * 128;
    const int n0  = blockIdx.y * 128;
    const int wr  = w >> 1, wc = w & 1;

    const int srow = 16 * w + (l >> 2);
    const int scol = (l & 3) * 8;
    const ushort* aptr = A + (size_t)(m0 + srow) * K + scol;
    const ushort* bptr = W + (size_t)(n0 + srow) * K + scol;
    ushort* asl = &As[w * 512];
    ushort* bsl = &Bs[w * 512];

    const int fl = l & 15, fk = (l >> 4) * 8;

    f32x4 acc[4][4] = {};

    for (int k0 = 0; k0 < K; k0 += 32) {
        __syncthreads();
        stage16(aptr + k0,                    asl);
        stage16(aptr + k0 + (size_t)64 * K,   asl + 2048);
        stage16(bptr + k0,                    bsl);
        stage16(bptr + k0 + (size_t)64 * K,   bsl + 2048);
        __syncthreads();

        short8 af[4], bf[4];
        #pragma unroll
        for (int i = 0; i < 4; ++i)
            af[i] = *(const short8*)&As[(wr * 64 + i * 16 + fl) * 32 + fk];
        #pragma unroll
        for (int j = 0; j < 4; ++j)
            bf[j] = *(const short8*)&Bs[(wc * 64 + j * 16 + fl) * 32 + fk];
        #pragma unroll
        for (int i = 0; i < 4; ++i)
            #pragma unroll
            for (int j = 0; j < 4; ++j)
                acc[i][j] = __builtin_amdgcn_mfma_f32_16x16x32_bf16(af[i], bf[j], acc[i][j], 0, 0, 0);
    }

    #pragma unroll
    for (int i = 0; i < 4; ++i) {
        #pragma unroll
        for (int j = 0; j < 4; ++j) {
            #pragma unroll
            for (int q = 0; q < 4; ++q) {
                const int m = m0 + wr * 64 + i * 16 + (l >> 4) * 4 + q;
                const int n = n0 + wc * 64 + j * 16 + fl;
                const float vv = acc[i][j][q];
                if (MODE == 0) {
                    const int b = m >> 10, s = m & 1023, h = n >> 6, d = n & 63;
                    Cb[(((size_t)b * NH + h) * NS + s) * ND + d] = f2bf(vv);
                } else if (MODE == 3) {
                    const int h = m >> 6, d = m & 63, b = n >> 10, s = n & 1023;
                    Cb[(((size_t)b * NH + h) * ND + d) * NS + s] = f2bf(vv);
                } else {
                    Cf[(size_t)m * NE + n] = vv;
                }
            }
        }
    }
}

// ---------------- MFMA fused attention with RPE ----------------
// 1 wave / block. XCD-aware block swizzle: each XCD owns 16 bh values and
// runs each bh's 32 s-tiles back-to-back (longest first) -> K/V/PEVT stay
// L2-resident per XCD (the latency that dominated rounds 2-10).
// Deferred skew GEMM (Pb parity dbuf); pek operands prefetched at iter top.
__global__ __launch_bounds__(64, 2)
void attn_mfma(const ushort* __restrict__ Qb, const ushort* __restrict__ Kb,
               const ushort* __restrict__ VTb, const ushort* __restrict__ PEKb,
               const ushort* __restrict__ PEVTs, ushort* __restrict__ AO)
{
    const int idx   = blockIdx.x;
    const int xcd   = idx & 7;           // HW round-robins blocks over 8 XCDs
    const int local = idx >> 3;          // 0..511 within this XCD
    const int bh    = xcd * 16 + (local >> 5);
    const int st    = 31 - (local & 31); // longest-first within each bh
    const int b     = bh >> 4, h = bh & 15;
    const int n2    = h * NB + b;        // torch view(S,H,B,S).transpose(0,2) shuffle
    const int b2    = n2 >> 4, h2 = n2 & 15;
    const int s0    = st * 32;

    const int lane = threadIdx.x;
    const int sl   = lane & 31;
    const int hi   = lane >> 5;

    // Mb: two 64-wide u-windows (parity = iter&1), stride 67 -> conflict-free diagonal
    __shared__ __align__(16) ushort Mb[2][32][67];
    __shared__ __align__(16) ushort Pb[2][32][72];   // parity double buffer

    for (int t = lane; t < 2 * 32 * 72 / 2; t += 64) ((int*)Pb)[t] = 0;

    const ushort* qptr  = Qb + (((size_t)bh * NS) + s0 + sl) * ND + hi * 8;
    const ushort* q2ptr = Qb + ((((size_t)b2 * NH + h2) * NS) + s0 + sl) * ND + hi * 8;
    short8 qf[4], q2f[4];
    #pragma unroll
    for (int c = 0; c < 4; ++c) {
        qf[c]  = *(const short8*)(qptr  + 16 * c);
        q2f[c] = *(const short8*)(q2ptr + 16 * c);
    }

    const ushort* kbase  = Kb  + (size_t)bh * NS * ND;
    const ushort* vtbase = VTb + (size_t)bh * ND * NS;
    const int RBASE = NL - 31 - s0;      // pek row base for chunk 0

    // chunk c with pre-loaded ef operands: M[s, 32c+u'], u' in [0,32);
    // lower copy -> Mb[c&1][*][u'], upper copy (window c-1) -> Mb[(c+1)&1][*][32+u']
    auto mchunk = [&](int c, int dual, const short8* ef) {
        f32x16 cm = {};
        #pragma unroll
        for (int c4 = 0; c4 < 4; ++c4)
            cm = __builtin_amdgcn_mfma_f32_32x32x16_bf16(q2f[c4], ef[c4], cm, 0, 0, 0);
        #pragma unroll
        for (int q = 0; q < 16; ++q) {
            const int srow = (q & 3) + 8 * (q >> 2) + 4 * hi;
            const ushort bb = f2bf(cm[q]);
            Mb[c & 1][srow][sl] = bb;
            if (dual) Mb[(c + 1) & 1][srow][32 + sl] = bb;
        }
    };

    f32x16 acc0 = {}, acc1 = {};
    float mrow = -1e30f, lrow = 0.f;

    // ---- prologue: chunks 0,1 and K fragments for iter 0 ----
    {
        short8 e0[4], e1[4];
        const ushort* pp0 = PEKb + (size_t)(RBASE + sl) * ND + hi * 8;
        const ushort* pp1 = PEKb + (size_t)(RBASE + 32 + sl) * ND + hi * 8;
        #pragma unroll
        for (int c4 = 0; c4 < 4; ++c4) {
            e0[c4] = *(const short8*)(pp0 + 16 * c4);
            e1[c4] = *(const short8*)(pp1 + 16 * c4);
        }
        __builtin_amdgcn_s_setprio(1);
        mchunk(0, 0, e0);
        mchunk(1, 1, e1);
        __builtin_amdgcn_s_setprio(0);
    }
    short8 kf[4], kfn[4];
    #pragma unroll
    for (int c = 0; c < 4; ++c)
        kf[c] = *(const short8*)(kbase + (size_t)sl * ND + hi * 8 + 16 * c);

    for (int i = 0; i <= st; ++i) {
        const int t0 = i * 32;
        const int R0 = t0 - s0 + NL - 31;
        const int p  = i & 1;

        // ---- pek prefetch for mchunk(i+2) (consumed mid-iteration) ----
        short8 efn[4];
        if (i < st) {
            const ushort* ppn = PEKb + (size_t)(RBASE + 32 * (i + 2) + sl) * ND + hi * 8;
            #pragma unroll
            for (int c4 = 0; c4 < 4; ++c4) efn[c4] = *(const short8*)(ppn + 16 * c4);
        }

        // ---- ea preload for the DEFERRED skew (window i-1) ----
        short8 ea[4][2];
        if (i > 0) {
            const ushort* pvp = PEVTs + (size_t)sl * 1056 + (R0 - 33) + 8 * hi;
            #pragma unroll
            for (int c = 0; c < 4; ++c) {
                ea[c][0] = *(const short8*)(pvp + 16 * c);
                ea[c][1] = *(const short8*)(pvp + 16 * c + (size_t)32 * 1056);
            }
        }

        // ---- V preload (used after softmax) ----
        short8 va[2][2];
        #pragma unroll
        for (int c = 0; c < 2; ++c) {
            const ushort* vt0 = vtbase + (size_t)sl * NS + t0 + 16 * c + 8 * hi;
            va[c][0] = *(const short8*)(vt0);
            va[c][1] = *(const short8*)(vt0 + 32 * NS);
        }

        // ---- QK^T (swapped): Csw[t,s] ----
        f32x16 csw = {};
        __builtin_amdgcn_s_setprio(1);
        #pragma unroll
        for (int c = 0; c < 4; ++c)
            csw = __builtin_amdgcn_mfma_f32_32x32x16_bf16(kf[c], qf[c], csw, 0, 0, 0);
        __builtin_amdgcn_s_setprio(0);

        // ---- K fragments for next iter ----
        if (i < st) {
            const ushort* kpn = kbase + (size_t)(t0 + 32 + sl) * ND + hi * 8;
            #pragma unroll
            for (int c = 0; c < 4; ++c) kfn[c] = *(const short8*)(kpn + 16 * c);
        }

        // ---- gather RPE; mask only on the diagonal tile ----
        float sc[16];
        #pragma unroll
        for (int q = 0; q < 16; ++q) {
            const int trow = (q & 3) + 8 * (q >> 2) + 4 * hi;
            const int u = trow + 31 - sl;
            sc[q] = (csw[q] + bf2f(Mb[p][sl][u])) * 0.125f;
        }
        if (i == st) {
            #pragma unroll
            for (int q = 0; q < 16; ++q) {
                const int trow = (q & 3) + 8 * (q >> 2) + 4 * hi;
                if (t0 + trow > s0 + sl) sc[q] = -1e30f;
            }
        }
        float tmax = -1e30f;
        #pragma unroll
        for (int q = 0; q < 16; ++q) tmax = fmaxf(tmax, sc[q]);

        // ---- DEFERRED skew GEMM for window i-1 (before rescale: exact) ----
        if (i > 0) {
            __builtin_amdgcn_s_setprio(1);
            #pragma unroll
            for (int c = 0; c < 4; ++c) {
                short8 pskew = *(const short8*)&Pb[p ^ 1][sl][16 * c + 8 * hi];
                acc0 = __builtin_amdgcn_mfma_f32_32x32x16_bf16(ea[c][0], pskew, acc0, 0, 0, 0);
                acc1 = __builtin_amdgcn_mfma_f32_32x32x16_bf16(ea[c][1], pskew, acc1, 0, 0, 0);
            }
            __builtin_amdgcn_s_setprio(0);
        }

        // ---- online softmax with defer-max (THR=8) ----
        tmax = fmaxf(tmax, __shfl_xor(tmax, 32));
        if (!__all(tmax <= mrow + 8.f)) {
            const float mnew = fmaxf(mrow, tmax);
            const float r = __expf(mrow - mnew);
            lrow *= r;
            acc0 *= r; acc1 *= r;
            mrow = mnew;
        }
        float ps[16], lsum = 0.f;
        #pragma unroll
        for (int q = 0; q < 16; ++q) { ps[q] = __expf(sc[q] - mrow); lsum += ps[q]; }
        lsum += __shfl_xor(lsum, 32);
        lrow += lsum;

        // ---- write Pskew (bf16) into parity buffer p ----
        #pragma unroll
        for (int q = 0; q < 16; ++q) {
            const int trow = (q & 3) + 8 * (q >> 2) + 4 * hi;
            Pb[p][sl][trow + 31 - sl] = f2bf(ps[q]);
        }

        // ---- next M chunk (i+2): window i+1 upper + window i+2 lower ----
        if (i < st) {
            __builtin_amdgcn_s_setprio(1);
            mchunk(i + 2, 1, efn);
            __builtin_amdgcn_s_setprio(0);
        }

        // ---- PV: O^T += V^T · P^T ----
        float sh[16];
        #pragma unroll
        for (int q = 0; q < 16; ++q) sh[q] = __shfl_xor(ps[q], 32);
        __builtin_amdgcn_s_setprio(1);
        #pragma unroll
        for (int c = 0; c < 2; ++c) {
            short8 bfrag;
            #pragma unroll
            for (int j = 0; j < 8; ++j) {
                float pv;
                if (j < 4) pv = hi ? sh[8 * c + 4 + j] : ps[8 * c + j];
                else       pv = hi ? ps[8 * c + j]     : sh[8 * c + j - 4];
                bfrag[j] = (short)f2bf(pv);
            }
            acc0 = __builtin_amdgcn_mfma_f32_32x32x16_bf16(va[c][0], bfrag, acc0, 0, 0, 0);
            acc1 = __builtin_amdgcn_mfma_f32_32x32x16_bf16(va[c][1], bfrag, acc1, 0, 0, 0);
        }
        __builtin_amdgcn_s_setprio(0);

        // ---- rotate K fragments ----
        if (i < st) {
            #pragma unroll
            for (int c = 0; c < 4; ++c) kf[c] = kfn[c];
        }
    }

    // ---- final skew GEMM for window st ----
    {
        const ushort* pvp = PEVTs + (size_t)sl * 1056 + (NL - 32) + 8 * hi;
        __builtin_amdgcn_s_setprio(1);
        #pragma unroll
        for (int c = 0; c < 4; ++c) {
            short8 e0 = *(const short8*)(pvp + 16 * c);
            short8 e1 = *(const short8*)(pvp + 16 * c + (size_t)32 * 1056);
            short8 pskew = *(const short8*)&Pb[st & 1][sl][16 * c + 8 * hi];
            acc0 = __builtin_amdgcn_mfma_f32_32x32x16_bf16(e0, pskew, acc0, 0, 0, 0);
            acc1 = __builtin_amdgcn_mfma_f32_32x32x16_bf16(e1, pskew, acc1, 0, 0, 0);
        }
        __builtin_amdgcn_s_setprio(0);
    }

    // ---- epilogue: bf16 packed stores ----
    const float inv = 1.0f / lrow;
    ushort* orow = AO + ((size_t)b * NS + s0 + sl) * NE + h * ND;
    #pragma unroll
    for (int g = 0; g < 4; ++g) {
        ushort4 o0 = make_ushort4(f2bf(acc0[4*g+0]*inv), f2bf(acc0[4*g+1]*inv),
                                  f2bf(acc0[4*g+2]*inv), f2bf(acc0[4*g+3]*inv));
        ushort4 o1 = make_ushort4(f2bf(acc1[4*g+0]*inv), f2bf(acc1[4*g+1]*inv),
                                  f2bf(acc1[4*g+2]*inv), f2bf(acc1[4*g+3]*inv));
        *(ushort4*)&orow[8 * g + 4 * hi]      = o0;
        *(ushort4*)&orow[8 * g + 4 * hi + 32] = o1;
    }
}

extern "C" void kernel_launch(void* const* d_in, const int* in_sizes, int n_in,
                              void* d_out, int out_size, void* d_ws, size_t ws_size,
                              hipStream_t stream) {
    const float* x   = (const float*)d_in[0];
    const float* Wq  = (const float*)d_in[2];
    const float* Wk  = (const float*)d_in[3];
    const float* Wv  = (const float*)d_in[4];
    const float* Wo  = (const float*)d_in[5];
    const float* pek = (const float*)d_in[6];
    const float* pev = (const float*)d_in[7];

    ushort* ws16 = (ushort*)d_ws;
    size_t off = 0;
    ushort* xb    = ws16 + off; off += (size_t)8388608;   // [8192,1024] bf16
    ushort* Wqb   = ws16 + off; off += (size_t)1048576;
    ushort* Wkb   = ws16 + off; off += (size_t)1048576;
    ushort* Wvb   = ws16 + off; off += (size_t)1048576;
    ushort* Wob   = ws16 + off; off += (size_t)1048576;
    ushort* Qb    = ws16 + off; off += (size_t)8388608;   // [B,H,S,D]
    ushort* Kbf   = ws16 + off; off += (size_t)8388608;   // [B,H,S,D]
    ushort* VTb   = ws16 + off; off += (size_t)8388608;   // [B,H,D,S]
    ushort* PEKb  = ws16 + off; off += (size_t)131136;    // [2049,64]
    ushort* PEVTs = ws16 + off; off += (size_t)67584;     // [64,1056]
    ushort* aob   = ws16 + off; off += (size_t)8388608;   // [B,S,E] bf16
    float*  out   = (float*)d_out;

    dim3 blk(256);
    cast_f2b4<<<8192, blk, 0, stream>>>(x, xb, 2097152);
    cast_w4<<<4096, blk, 0, stream>>>(Wq, Wk, Wv, Wo, Wqb);
    cast_pek<<<(2049 * 64 + 255) / 256, blk, 0, stream>>>(pek, PEKb, 2049 * 64);
    cast_pevt<<<(64 * 1056 + 255) / 256, blk, 0, stream>>>(pev, PEVTs);

    gemm_mfma<0><<<dim3(64, 8), blk, 0, stream>>>(xb, Wqb, nullptr, Qb);
    gemm_mfma<0><<<dim3(64, 8), blk, 0, stream>>>(xb, Wkb, nullptr, Kbf);
    gemm_mfma<3><<<dim3(8, 64), blk, 0, stream>>>(Wvb, xb, nullptr, VTb);

    attn_mfma<<<dim3(4096), dim3(64), 0, stream>>>(Qb, Kbf, VTb, PEKb, PEVTs, aob);

    gemm_mfma<1><<<dim3(64, 8), blk, 0, stream>>>(aob, Wob, out, nullptr);
}

// Round 13
// 237.112 us; speedup vs baseline: 1.2986x; 1.2986x over previous
//
#include <hip/hip_runtime.h>
#include <math.h>

#define NB 8
#define NS 1024
#define NE 1024
#define NH 16
#define ND 64
#define NL 1024

typedef __attribute__((ext_vector_type(8))) short short8;
typedef __attribute__((ext_vector_type(4))) float f32x4;
typedef __attribute__((ext_vector_type(16))) float f32x16;

__device__ __forceinline__ ushort f2bf(float f) {
    union { float f; unsigned u; } v; v.f = f;
    unsigned r = v.u + 0x7fffu + ((v.u >> 16) & 1u);
    return (ushort)(r >> 16);
}
__device__ __forceinline__ float bf2f(ushort u) {
    union { unsigned u; float f; } v; v.u = ((unsigned)u) << 16;
    return v.f;
}

__device__ __forceinline__ void stage16(const ushort* gsrc, ushort* lbase) {
    __builtin_amdgcn_global_load_lds((const __attribute__((address_space(1))) void*)gsrc,
                                     (__attribute__((address_space(3))) void*)lbase,
                                     16, 0, 0);
}

// ---------------- casts ----------------
__global__ __launch_bounds__(256)
void cast_f2b4(const float* __restrict__ in, ushort* __restrict__ out, int n4) {
    int i = blockIdx.x * 256 + threadIdx.x;
    if (i >= n4) return;
    float4 v = ((const float4*)in)[i];
    ((ushort4*)out)[i] = make_ushort4(f2bf(v.x), f2bf(v.y), f2bf(v.z), f2bf(v.w));
}

// all four weights -> consecutive bf16 buffers (Wqb|Wkb|Wvb|Wob)
__global__ __launch_bounds__(256)
void cast_w4(const float* __restrict__ Wq, const float* __restrict__ Wk,
             const float* __restrict__ Wv, const float* __restrict__ Wo,
             ushort* __restrict__ out) {
    int i = blockIdx.x * 256 + threadIdx.x;   // [0, 4*262144)
    const int seg = i >> 18, j = i & 262143;
    const float* src = seg == 0 ? Wq : seg == 1 ? Wk : seg == 2 ? Wv : Wo;
    float4 v = ((const float4*)src)[j];
    ((ushort4*)out)[i] = make_ushort4(f2bf(v.x), f2bf(v.y), f2bf(v.z), f2bf(v.w));
}

// PEK fragment-major: PEKf[c4][r][d&15], c4 = d>>4  (offset = c4*32784 + r*16 + (d&15))
__global__ __launch_bounds__(256)
void cast_pek(const float* __restrict__ pek, ushort* __restrict__ out, int n) {
    int i = blockIdx.x * 256 + threadIdx.x;
    if (i >= n) return;
    const int r = i >> 6, d = i & 63;
    out[(size_t)(d >> 4) * 32784 + (size_t)r * 16 + (d & 15)] = f2bf(pek[i]);
}

// PEV fragment-major (value shifted by 1 row as before):
// element (d, r') with r' in [0,1056): m=r'>>5, cc=(r'>>4)&1, hi=(r'>>3)&1, j=r'&7,
// a=d>>5, sl=d&31 -> offset = m*2048 + cc*1024 + a*512 + (sl*2+hi)*8 + j
__global__ __launch_bounds__(256)
void cast_pevt(const float* __restrict__ pev, ushort* __restrict__ out) {
    int i = blockIdx.x * 256 + threadIdx.x;
    if (i >= 64 * 1056) return;
    const int d = i / 1056, r = i % 1056;
    const int m = r >> 5, cc = (r >> 4) & 1, hi = (r >> 3) & 1, j = r & 7;
    const int a = d >> 5, sl = d & 31;
    out[(size_t)m * 2048 + cc * 1024 + a * 512 + (sl * 2 + hi) * 8 + j] =
        f2bf(pev[(size_t)(r + 1) * ND + d]);
}

// ---------------- MFMA GEMM: C = A @ W^T (bf16 in, fp32 acc) ----------------
// MODE 0: bf16 row-major scatter -> [B,H,S,D]            (Q)
// MODE 1: fp32 row-major [M,1024]                        (out-proj)
// MODE 3: operands (Wv, x); V fragment-major             (V)
// MODE 4: K fragment-major                               (K)
template<int MODE>
__global__ __launch_bounds__(256)
void gemm_mfma(const ushort* __restrict__ A, const ushort* __restrict__ W,
               float* __restrict__ Cf, ushort* __restrict__ Cb)
{
    constexpr int K = 1024;
    __shared__ __align__(16) ushort As[128 * 32];
    __shared__ __align__(16) ushort Bs[128 * 32];
    const int tid = threadIdx.x;
    const int w   = tid >> 6;
    const int l   = tid & 63;
    const int m0  = blockIdx.x * 128;
    const int n0  = blockIdx.y * 128;
    const int wr  = w >> 1, wc = w & 1;

    const int srow = 16 * w + (l >> 2);
    const int scol = (l & 3) * 8;
    const ushort* aptr = A + (size_t)(m0 + srow) * K + scol;
    const ushort* bptr = W + (size_t)(n0 + srow) * K + scol;
    ushort* asl = &As[w * 512];
    ushort* bsl = &Bs[w * 512];

    const int fl = l & 15, fk = (l >> 4) * 8;

    f32x4 acc[4][4] = {};

    for (int k0 = 0; k0 < K; k0 += 32) {
        __syncthreads();
        stage16(aptr + k0,                    asl);
        stage16(aptr + k0 + (size_t)64 * K,   asl + 2048);
        stage16(bptr + k0,                    bsl);
        stage16(bptr + k0 + (size_t)64 * K,   bsl + 2048);
        __syncthreads();

        short8 af[4], bf[4];
        #pragma unroll
        for (int i = 0; i < 4; ++i)
            af[i] = *(const short8*)&As[(wr * 64 + i * 16 + fl) * 32 + fk];
        #pragma unroll
        for (int j = 0; j < 4; ++j)
            bf[j] = *(const short8*)&Bs[(wc * 64 + j * 16 + fl) * 32 + fk];
        #pragma unroll
        for (int i = 0; i < 4; ++i)
            #pragma unroll
            for (int j = 0; j < 4; ++j)
                acc[i][j] = __builtin_amdgcn_mfma_f32_16x16x32_bf16(af[i], bf[j], acc[i][j], 0, 0, 0);
    }

    #pragma unroll
    for (int i = 0; i < 4; ++i) {
        #pragma unroll
        for (int j = 0; j < 4; ++j) {
            #pragma unroll
            for (int q = 0; q < 4; ++q) {
                const int m = m0 + wr * 64 + i * 16 + (l >> 4) * 4 + q;
                const int n = n0 + wc * 64 + j * 16 + fl;
                const float vv = acc[i][j][q];
                if (MODE == 0) {
                    const int b = m >> 10, s = m & 1023, h = n >> 6, d = n & 63;
                    Cb[(((size_t)b * NH + h) * NS + s) * ND + d] = f2bf(vv);
                } else if (MODE == 4) {
                    const int bh = (m >> 10) * 16 + (n >> 6), t = m & 1023, d = n & 63;
                    Cb[((size_t)bh * 4 + (d >> 4)) * 16384 + (size_t)t * 16 + (d & 15)] = f2bf(vv);
                } else if (MODE == 3) {
                    const int h = m >> 6, d = m & 63, b = n >> 10, s = n & 1023;
                    const int bh = b * 16 + h;
                    const int it = s >> 5, trel = s & 31;
                    const int c = trel >> 4, hi = (trel >> 3) & 1, jj = trel & 7;
                    const int a = d >> 5, sl = d & 31;
                    Cb[(size_t)bh * 65536 + it * 2048 +
                       ((a * 2 + c) * 64 + sl * 2 + hi) * 8 + jj] = f2bf(vv);
                } else {
                    Cf[(size_t)m * NE + n] = vv;
                }
            }
        }
    }
}

// ---------------- MFMA fused attention with RPE ----------------
// 1 wave / block (round-10 verified structure + fragment-major operands).
// All per-iteration global loads are contiguous-1KB wave accesses.
// Post-consumption reloads give ~1-iteration prefetch with zero extra regs.
__global__ __launch_bounds__(64, 2)
void attn_mfma(const ushort* __restrict__ Qb, const ushort* __restrict__ Kf_,
               const ushort* __restrict__ Vf_, const ushort* __restrict__ PEKf,
               const ushort* __restrict__ PEVf, ushort* __restrict__ AO)
{
    const int idx = blockIdx.x;
    const int st  = 31 - (idx >> 7);     // longest blocks first
    const int bh  = idx & 127;
    const int b   = bh >> 4, h = bh & 15;
    const int n2  = h * NB + b;          // torch view(S,H,B,S).transpose(0,2) shuffle
    const int b2  = n2 >> 4, h2 = n2 & 15;
    const int s0  = st * 32;

    const int lane = threadIdx.x;
    const int sl   = lane & 31;
    const int hi   = lane >> 5;

    __shared__ __align__(16) ushort Mb[2][32][67];
    __shared__ __align__(16) ushort Pb[2][32][72];

    for (int t = lane; t < 2 * 32 * 72 / 2; t += 64) ((int*)Pb)[t] = 0;

    const ushort* qptr  = Qb + (((size_t)bh * NS) + s0 + sl) * ND + hi * 8;
    const ushort* q2ptr = Qb + ((((size_t)b2 * NH + h2) * NS) + s0 + sl) * ND + hi * 8;
    short8 qf[4], q2f[4];
    #pragma unroll
    for (int c = 0; c < 4; ++c) {
        qf[c]  = *(const short8*)(qptr  + 16 * c);
        q2f[c] = *(const short8*)(q2ptr + 16 * c);
    }

    // fragment-major bases (lane-resolved)
    const ushort* kfb  = Kf_ + (size_t)bh * 65536 + sl * 16 + hi * 8;   // + c*16384 + t*16
    const ushort* vfb  = Vf_ + (size_t)bh * 65536 + (sl * 2 + hi) * 8;  // + i*2048 + (a*2+c)*512
    const ushort* efb  = PEKf + sl * 16 + hi * 8;                       // + c4*32784 + r*16
    const ushort* pevw = PEVf + (size_t)(31 - st) * 2048 + (sl * 2 + hi) * 8;
                                                   // window w: + w*2048 + (c>>1)*2048 + (c&1)*1024 + a*512
    const int RBASE = NL - 31 - s0;

    auto mchunk = [&](int c, int dual, const short8* ef) {
        f32x16 cm = {};
        #pragma unroll
        for (int c4 = 0; c4 < 4; ++c4)
            cm = __builtin_amdgcn_mfma_f32_32x32x16_bf16(q2f[c4], ef[c4], cm, 0, 0, 0);
        #pragma unroll
        for (int q = 0; q < 16; ++q) {
            const int srow = (q & 3) + 8 * (q >> 2) + 4 * hi;
            const ushort bb = f2bf(cm[q]);
            Mb[c & 1][srow][sl] = bb;
            if (dual) Mb[(c + 1) & 1][srow][32 + sl] = bb;
        }
    };

    f32x16 acc0 = {}, acc1 = {};
    float mrow = -1e30f, lrow = 0.f;
    short8 kf[4], va[2][2], ea[4][2], efn[4];

    // ---- prologue ----
    {
        short8 e0[4], e1[4];
        #pragma unroll
        for (int c4 = 0; c4 < 4; ++c4) {
            e0[c4] = *(const short8*)(efb + (size_t)c4 * 32784 + (size_t)RBASE * 16);
            e1[c4] = *(const short8*)(efb + (size_t)c4 * 32784 + (size_t)(RBASE + 32) * 16);
        }
        __builtin_amdgcn_s_setprio(1);
        mchunk(0, 0, e0);
        mchunk(1, 1, e1);
        __builtin_amdgcn_s_setprio(0);
    }
    #pragma unroll
    for (int c = 0; c < 4; ++c)
        kf[c] = *(const short8*)(kfb + c * 16384);
    #pragma unroll
    for (int c = 0; c < 2; ++c)
        #pragma unroll
        for (int a = 0; a < 2; ++a)
            va[c][a] = *(const short8*)(vfb + (a * 2 + c) * 512);
    if (st >= 1) {
        #pragma unroll
        for (int c4 = 0; c4 < 4; ++c4)
            efn[c4] = *(const short8*)(efb + (size_t)c4 * 32784 + (size_t)(RBASE + 64) * 16);
    }

    for (int i = 0; i <= st; ++i) {
        const int t0 = i * 32;
        const int p  = i & 1;

        // ---- QK^T (swapped): Csw[t,s] ----
        f32x16 csw = {};
        __builtin_amdgcn_s_setprio(1);
        #pragma unroll
        for (int c = 0; c < 4; ++c)
            csw = __builtin_amdgcn_mfma_f32_32x32x16_bf16(kf[c], qf[c], csw, 0, 0, 0);
        __builtin_amdgcn_s_setprio(0);

        // ---- reload K for next iter (post-consumption; ~1 iter of cover) ----
        if (i < st) {
            #pragma unroll
            for (int c = 0; c < 4; ++c)
                kf[c] = *(const short8*)(kfb + c * 16384 + (size_t)(t0 + 32) * 16);
        }

        // ---- gather RPE; mask only on the diagonal tile ----
        float sc[16];
        #pragma unroll
        for (int q = 0; q < 16; ++q) {
            const int trow = (q & 3) + 8 * (q >> 2) + 4 * hi;
            const int u = trow + 31 - sl;
            sc[q] = (csw[q] + bf2f(Mb[p][sl][u])) * 0.125f;
        }
        if (i == st) {
            #pragma unroll
            for (int q = 0; q < 16; ++q) {
                const int trow = (q & 3) + 8 * (q >> 2) + 4 * hi;
                if (t0 + trow > s0 + sl) sc[q] = -1e30f;
            }
        }
        float tmax = -1e30f;
        #pragma unroll
        for (int q = 0; q < 16; ++q) tmax = fmaxf(tmax, sc[q]);

        // ---- DEFERRED skew GEMM for window i-1 (before rescale: exact) ----
        if (i > 0) {
            __builtin_amdgcn_s_setprio(1);
            #pragma unroll
            for (int c = 0; c < 4; ++c) {
                short8 pskew = *(const short8*)&Pb[p ^ 1][sl][16 * c + 8 * hi];
                acc0 = __builtin_amdgcn_mfma_f32_32x32x16_bf16(ea[c][0], pskew, acc0, 0, 0, 0);
                acc1 = __builtin_amdgcn_mfma_f32_32x32x16_bf16(ea[c][1], pskew, acc1, 0, 0, 0);
            }
            __builtin_amdgcn_s_setprio(0);
        }

        // ---- load ea for window i (used at next iter's skew / final skew) ----
        #pragma unroll
        for (int c = 0; c < 4; ++c)
            #pragma unroll
            for (int a = 0; a < 2; ++a)
                ea[c][a] = *(const short8*)(pevw + (size_t)(i + (c >> 1)) * 2048 +
                                            (c & 1) * 1024 + a * 512);

        // ---- online softmax with defer-max (THR=8) ----
        tmax = fmaxf(tmax, __shfl_xor(tmax, 32));
        if (!__all(tmax <= mrow + 8.f)) {
            const float mnew = fmaxf(mrow, tmax);
            const float r = __expf(mrow - mnew);
            lrow *= r;
            acc0 *= r; acc1 *= r;
            mrow = mnew;
        }
        float ps[16], lsum = 0.f;
        #pragma unroll
        for (int q = 0; q < 16; ++q) { ps[q] = __expf(sc[q] - mrow); lsum += ps[q]; }
        lsum += __shfl_xor(lsum, 32);
        lrow += lsum;

        // ---- write Pskew (bf16) into parity buffer p ----
        #pragma unroll
        for (int q = 0; q < 16; ++q) {
            const int trow = (q & 3) + 8 * (q >> 2) + 4 * hi;
            Pb[p][sl][trow + 31 - sl] = f2bf(ps[q]);
        }

        // ---- next M chunk (i+2) + pek prefetch for chunk i+3 ----
        if (i < st) {
            __builtin_amdgcn_s_setprio(1);
            mchunk(i + 2, 1, efn);
            __builtin_amdgcn_s_setprio(0);
            if (i + 1 < st) {
                #pragma unroll
                for (int c4 = 0; c4 < 4; ++c4)
                    efn[c4] = *(const short8*)(efb + (size_t)c4 * 32784 +
                                               (size_t)(RBASE + 32 * (i + 3)) * 16);
            }
        }

        // ---- PV: O^T += V^T · P^T ----
        float sh[16];
        #pragma unroll
        for (int q = 0; q < 16; ++q) sh[q] = __shfl_xor(ps[q], 32);
        __builtin_amdgcn_s_setprio(1);
        #pragma unroll
        for (int c = 0; c < 2; ++c) {
            short8 bfrag;
            #pragma unroll
            for (int j = 0; j < 8; ++j) {
                float pv;
                if (j < 4) pv = hi ? sh[8 * c + 4 + j] : ps[8 * c + j];
                else       pv = hi ? ps[8 * c + j]     : sh[8 * c + j - 4];
                bfrag[j] = (short)f2bf(pv);
            }
            acc0 = __builtin_amdgcn_mfma_f32_32x32x16_bf16(va[c][0], bfrag, acc0, 0, 0, 0);
            acc1 = __builtin_amdgcn_mfma_f32_32x32x16_bf16(va[c][1], bfrag, acc1, 0, 0, 0);
        }
        __builtin_amdgcn_s_setprio(0);

        // ---- reload V for next iter (post-consumption) ----
        if (i < st) {
            #pragma unroll
            for (int c = 0; c < 2; ++c)
                #pragma unroll
                for (int a = 0; a < 2; ++a)
                    va[c][a] = *(const short8*)(vfb + (size_t)(i + 1) * 2048 + (a * 2 + c) * 512);
        }
    }

    // ---- final skew GEMM for window st (ea loaded at iter st) ----
    {
        __builtin_amdgcn_s_setprio(1);
        #pragma unroll
        for (int c = 0; c < 4; ++c) {
            short8 pskew = *(const short8*)&Pb[st & 1][sl][16 * c + 8 * hi];
            acc0 = __builtin_amdgcn_mfma_f32_32x32x16_bf16(ea[c][0], pskew, acc0, 0, 0, 0);
            acc1 = __builtin_amdgcn_mfma_f32_32x32x16_bf16(ea[c][1], pskew, acc1, 0, 0, 0);
        }
        __builtin_amdgcn_s_setprio(0);
    }

    // ---- epilogue: bf16 packed stores ----
    const float inv = 1.0f / lrow;
    ushort* orow = AO + ((size_t)b * NS + s0 + sl) * NE + h * ND;
    #pragma unroll
    for (int g = 0; g < 4; ++g) {
        ushort4 o0 = make_ushort4(f2bf(acc0[4*g+0]*inv), f2bf(acc0[4*g+1]*inv),
                                  f2bf(acc0[4*g+2]*inv), f2bf(acc0[4*g+3]*inv));
        ushort4 o1 = make_ushort4(f2bf(acc1[4*g+0]*inv), f2bf(acc1[4*g+1]*inv),
                                  f2bf(acc1[4*g+2]*inv), f2bf(acc1[4*g+3]*inv));
        *(ushort4*)&orow[8 * g + 4 * hi]      = o0;
        *(ushort4*)&orow[8 * g + 4 * hi + 32] = o1;
    }
}

extern "C" void kernel_launch(void* const* d_in, const int* in_sizes, int n_in,
                              void* d_out, int out_size, void* d_ws, size_t ws_size,
                              hipStream_t stream) {
    const float* x   = (const float*)d_in[0];
    const float* Wq  = (const float*)d_in[2];
    const float* Wk  = (const float*)d_in[3];
    const float* Wv  = (const float*)d_in[4];
    const float* Wo  = (const float*)d_in[5];
    const float* pek = (const float*)d_in[6];
    const float* pev = (const float*)d_in[7];

    ushort* ws16 = (ushort*)d_ws;
    size_t off = 0;
    ushort* xb    = ws16 + off; off += (size_t)8388608;   // [8192,1024] bf16
    ushort* Wqb   = ws16 + off; off += (size_t)1048576;
    ushort* Wkb   = ws16 + off; off += (size_t)1048576;
    ushort* Wvb   = ws16 + off; off += (size_t)1048576;
    ushort* Wob   = ws16 + off; off += (size_t)1048576;
    ushort* Qb    = ws16 + off; off += (size_t)8388608;   // [B,H,S,D] row-major
    ushort* Kfm   = ws16 + off; off += (size_t)8388608;   // K fragment-major
    ushort* Vfm   = ws16 + off; off += (size_t)8388608;   // V fragment-major
    ushort* PEKf  = ws16 + off; off += (size_t)131136;    // pek fragment-major
    ushort* PEVf  = ws16 + off; off += (size_t)67584;     // pev fragment-major
    ushort* aob   = ws16 + off; off += (size_t)8388608;   // [B,S,E] bf16
    float*  out   = (float*)d_out;

    dim3 blk(256);
    cast_f2b4<<<8192, blk, 0, stream>>>(x, xb, 2097152);
    cast_w4<<<4096, blk, 0, stream>>>(Wq, Wk, Wv, Wo, Wqb);
    cast_pek<<<(2049 * 64 + 255) / 256, blk, 0, stream>>>(pek, PEKf, 2049 * 64);
    cast_pevt<<<(64 * 1056 + 255) / 256, blk, 0, stream>>>(pev, PEVf);

    gemm_mfma<0><<<dim3(64, 8), blk, 0, stream>>>(xb, Wqb, nullptr, Qb);
    gemm_mfma<4><<<dim3(64, 8), blk, 0, stream>>>(xb, Wkb, nullptr, Kfm);
    gemm_mfma<3><<<dim3(8, 64), blk, 0, stream>>>(Wvb, xb, nullptr, Vfm);

    attn_mfma<<<dim3(4096), dim3(64), 0, stream>>>(Qb, Kfm, Vfm, PEKf, PEVf, aob);

    gemm_mfma<1><<<dim3(64, 8), blk, 0, stream>>>(aob, Wob, out, nullptr);
}

// Round 14
// 234.099 us; speedup vs baseline: 1.3153x; 1.0129x over previous
//
#include <hip/hip_runtime.h>
#include <math.h>

#define NB 8
#define NS 1024
#define NE 1024
#define NH 16
#define ND 64
#define NL 1024

typedef __attribute__((ext_vector_type(8))) short short8;
typedef __attribute__((ext_vector_type(4))) float f32x4;
typedef __attribute__((ext_vector_type(16))) float f32x16;

// native HW bf16 conversion (v_cvt on gfx950, RNE — same rounding as the
// previous software emulation, ~1 instr instead of ~5)
__device__ __forceinline__ ushort f2bf(float f) {
    union { __bf16 h; ushort u; } v;
    v.h = (__bf16)f;
    return v.u;
}
__device__ __forceinline__ float bf2f(ushort u) {
    union { unsigned u; float f; } v; v.u = ((unsigned)u) << 16;
    return v.f;
}

__device__ __forceinline__ void stage16(const ushort* gsrc, ushort* lbase) {
    __builtin_amdgcn_global_load_lds((const __attribute__((address_space(1))) void*)gsrc,
                                     (__attribute__((address_space(3))) void*)lbase,
                                     16, 0, 0);
}

// ---------------- casts ----------------
__global__ __launch_bounds__(256)
void cast_f2b4(const float* __restrict__ in, ushort* __restrict__ out, int n4) {
    int i = blockIdx.x * 256 + threadIdx.x;
    if (i >= n4) return;
    float4 v = ((const float4*)in)[i];
    ((ushort4*)out)[i] = make_ushort4(f2bf(v.x), f2bf(v.y), f2bf(v.z), f2bf(v.w));
}

// all four weights -> consecutive bf16 buffers (Wqb|Wkb|Wvb|Wob)
__global__ __launch_bounds__(256)
void cast_w4(const float* __restrict__ Wq, const float* __restrict__ Wk,
             const float* __restrict__ Wv, const float* __restrict__ Wo,
             ushort* __restrict__ out) {
    int i = blockIdx.x * 256 + threadIdx.x;   // [0, 4*262144)
    const int seg = i >> 18, j = i & 262143;
    const float* src = seg == 0 ? Wq : seg == 1 ? Wk : seg == 2 ? Wv : Wo;
    float4 v = ((const float4*)src)[j];
    ((ushort4*)out)[i] = make_ushort4(f2bf(v.x), f2bf(v.y), f2bf(v.z), f2bf(v.w));
}

// PEK fragment-major: PEKf[c4][r][d&15], c4 = d>>4  (offset = c4*32784 + r*16 + (d&15))
__global__ __launch_bounds__(256)
void cast_pek(const float* __restrict__ pek, ushort* __restrict__ out, int n) {
    int i = blockIdx.x * 256 + threadIdx.x;
    if (i >= n) return;
    const int r = i >> 6, d = i & 63;
    out[(size_t)(d >> 4) * 32784 + (size_t)r * 16 + (d & 15)] = f2bf(pek[i]);
}

// PEV fragment-major (value shifted by 1 row as before):
// element (d, r') with r' in [0,1056): m=r'>>5, cc=(r'>>4)&1, hi=(r'>>3)&1, j=r'&7,
// a=d>>5, sl=d&31 -> offset = m*2048 + cc*1024 + a*512 + (sl*2+hi)*8 + j
__global__ __launch_bounds__(256)
void cast_pevt(const float* __restrict__ pev, ushort* __restrict__ out) {
    int i = blockIdx.x * 256 + threadIdx.x;
    if (i >= 64 * 1056) return;
    const int d = i / 1056, r = i % 1056;
    const int m = r >> 5, cc = (r >> 4) & 1, hi = (r >> 3) & 1, j = r & 7;
    const int a = d >> 5, sl = d & 31;
    out[(size_t)m * 2048 + cc * 1024 + a * 512 + (sl * 2 + hi) * 8 + j] =
        f2bf(pev[(size_t)(r + 1) * ND + d]);
}

// ---------------- MFMA GEMM: C = A @ W^T (bf16 in, fp32 acc) ----------------
// MODE 0: bf16 row-major scatter -> [B,H,S,D]            (Q)
// MODE 1: fp32 row-major [M,1024]                        (out-proj)
// MODE 3: operands (Wv, x); V fragment-major             (V)
// MODE 4: K fragment-major                               (K)
template<int MODE>
__global__ __launch_bounds__(256)
void gemm_mfma(const ushort* __restrict__ A, const ushort* __restrict__ W,
               float* __restrict__ Cf, ushort* __restrict__ Cb)
{
    constexpr int K = 1024;
    __shared__ __align__(16) ushort As[128 * 32];
    __shared__ __align__(16) ushort Bs[128 * 32];
    const int tid = threadIdx.x;
    const int w   = tid >> 6;
    const int l   = tid & 63;
    const int m0  = blockIdx.x * 128;
    const int n0  = blockIdx.y * 128;
    const int wr  = w >> 1, wc = w & 1;

    const int srow = 16 * w + (l >> 2);
    const int scol = (l & 3) * 8;
    const ushort* aptr = A + (size_t)(m0 + srow) * K + scol;
    const ushort* bptr = W + (size_t)(n0 + srow) * K + scol;
    ushort* asl = &As[w * 512];
    ushort* bsl = &Bs[w * 512];

    const int fl = l & 15, fk = (l >> 4) * 8;

    f32x4 acc[4][4] = {};

    for (int k0 = 0; k0 < K; k0 += 32) {
        __syncthreads();
        stage16(aptr + k0,                    asl);
        stage16(aptr + k0 + (size_t)64 * K,   asl + 2048);
        stage16(bptr + k0,                    bsl);
        stage16(bptr + k0 + (size_t)64 * K,   bsl + 2048);
        __syncthreads();

        short8 af[4], bf[4];
        #pragma unroll
        for (int i = 0; i < 4; ++i)
            af[i] = *(const short8*)&As[(wr * 64 + i * 16 + fl) * 32 + fk];
        #pragma unroll
        for (int j = 0; j < 4; ++j)
            bf[j] = *(const short8*)&Bs[(wc * 64 + j * 16 + fl) * 32 + fk];
        #pragma unroll
        for (int i = 0; i < 4; ++i)
            #pragma unroll
            for (int j = 0; j < 4; ++j)
                acc[i][j] = __builtin_amdgcn_mfma_f32_16x16x32_bf16(af[i], bf[j], acc[i][j], 0, 0, 0);
    }

    #pragma unroll
    for (int i = 0; i < 4; ++i) {
        #pragma unroll
        for (int j = 0; j < 4; ++j) {
            #pragma unroll
            for (int q = 0; q < 4; ++q) {
                const int m = m0 + wr * 64 + i * 16 + (l >> 4) * 4 + q;
                const int n = n0 + wc * 64 + j * 16 + fl;
                const float vv = acc[i][j][q];
                if (MODE == 0) {
                    const int b = m >> 10, s = m & 1023, h = n >> 6, d = n & 63;
                    Cb[(((size_t)b * NH + h) * NS + s) * ND + d] = f2bf(vv);
                } else if (MODE == 4) {
                    const int bh = (m >> 10) * 16 + (n >> 6), t = m & 1023, d = n & 63;
                    Cb[((size_t)bh * 4 + (d >> 4)) * 16384 + (size_t)t * 16 + (d & 15)] = f2bf(vv);
                } else if (MODE == 3) {
                    const int h = m >> 6, d = m & 63, b = n >> 10, s = n & 1023;
                    const int bh = b * 16 + h;
                    const int it = s >> 5, trel = s & 31;
                    const int c = trel >> 4, hi = (trel >> 3) & 1, jj = trel & 7;
                    const int a = d >> 5, sl = d & 31;
                    Cb[(size_t)bh * 65536 + it * 2048 +
                       ((a * 2 + c) * 64 + sl * 2 + hi) * 8 + jj] = f2bf(vv);
                } else {
                    Cf[(size_t)m * NE + n] = vv;
                }
            }
        }
    }
}

// ---------------- MFMA fused attention with RPE ----------------
// 1 wave / block (round-12 verified structure). Fragment-major operands;
// deferred skew GEMM; native bf16 cvt; tree reductions for tmax/lsum.
__global__ __launch_bounds__(64, 2)
void attn_mfma(const ushort* __restrict__ Qb, const ushort* __restrict__ Kf_,
               const ushort* __restrict__ Vf_, const ushort* __restrict__ PEKf,
               const ushort* __restrict__ PEVf, ushort* __restrict__ AO)
{
    const int idx = blockIdx.x;
    const int st  = 31 - (idx >> 7);     // longest blocks first
    const int bh  = idx & 127;
    const int b   = bh >> 4, h = bh & 15;
    const int n2  = h * NB + b;          // torch view(S,H,B,S).transpose(0,2) shuffle
    const int b2  = n2 >> 4, h2 = n2 & 15;
    const int s0  = st * 32;

    const int lane = threadIdx.x;
    const int sl   = lane & 31;
    const int hi   = lane >> 5;

    __shared__ __align__(16) ushort Mb[2][32][67];
    __shared__ __align__(16) ushort Pb[2][32][72];

    for (int t = lane; t < 2 * 32 * 72 / 2; t += 64) ((int*)Pb)[t] = 0;

    const ushort* qptr  = Qb + (((size_t)bh * NS) + s0 + sl) * ND + hi * 8;
    const ushort* q2ptr = Qb + ((((size_t)b2 * NH + h2) * NS) + s0 + sl) * ND + hi * 8;
    short8 qf[4], q2f[4];
    #pragma unroll
    for (int c = 0; c < 4; ++c) {
        qf[c]  = *(const short8*)(qptr  + 16 * c);
        q2f[c] = *(const short8*)(q2ptr + 16 * c);
    }

    // fragment-major bases (lane-resolved)
    const ushort* kfb  = Kf_ + (size_t)bh * 65536 + sl * 16 + hi * 8;   // + c*16384 + t*16
    const ushort* vfb  = Vf_ + (size_t)bh * 65536 + (sl * 2 + hi) * 8;  // + i*2048 + (a*2+c)*512
    const ushort* efb  = PEKf + sl * 16 + hi * 8;                       // + c4*32784 + r*16
    const ushort* pevw = PEVf + (size_t)(31 - st) * 2048 + (sl * 2 + hi) * 8;
    const int RBASE = NL - 31 - s0;

    auto mchunk = [&](int c, int dual, const short8* ef) {
        f32x16 cm = {};
        #pragma unroll
        for (int c4 = 0; c4 < 4; ++c4)
            cm = __builtin_amdgcn_mfma_f32_32x32x16_bf16(q2f[c4], ef[c4], cm, 0, 0, 0);
        #pragma unroll
        for (int q = 0; q < 16; ++q) {
            const int srow = (q & 3) + 8 * (q >> 2) + 4 * hi;
            const ushort bb = f2bf(cm[q]);
            Mb[c & 1][srow][sl] = bb;
            if (dual) Mb[(c + 1) & 1][srow][32 + sl] = bb;
        }
    };

    f32x16 acc0 = {}, acc1 = {};
    float mrow = -1e30f, lrow = 0.f;
    short8 kf[4], va[2][2], ea[4][2], efn[4];

    // ---- prologue ----
    {
        short8 e0[4], e1[4];
        #pragma unroll
        for (int c4 = 0; c4 < 4; ++c4) {
            e0[c4] = *(const short8*)(efb + (size_t)c4 * 32784 + (size_t)RBASE * 16);
            e1[c4] = *(const short8*)(efb + (size_t)c4 * 32784 + (size_t)(RBASE + 32) * 16);
        }
        __builtin_amdgcn_s_setprio(1);
        mchunk(0, 0, e0);
        mchunk(1, 1, e1);
        __builtin_amdgcn_s_setprio(0);
    }
    #pragma unroll
    for (int c = 0; c < 4; ++c)
        kf[c] = *(const short8*)(kfb + c * 16384);
    #pragma unroll
    for (int c = 0; c < 2; ++c)
        #pragma unroll
        for (int a = 0; a < 2; ++a)
            va[c][a] = *(const short8*)(vfb + (a * 2 + c) * 512);
    if (st >= 1) {
        #pragma unroll
        for (int c4 = 0; c4 < 4; ++c4)
            efn[c4] = *(const short8*)(efb + (size_t)c4 * 32784 + (size_t)(RBASE + 64) * 16);
    }

    for (int i = 0; i <= st; ++i) {
        const int t0 = i * 32;
        const int p  = i & 1;

        // ---- QK^T (swapped): Csw[t,s] ----
        f32x16 csw = {};
        __builtin_amdgcn_s_setprio(1);
        #pragma unroll
        for (int c = 0; c < 4; ++c)
            csw = __builtin_amdgcn_mfma_f32_32x32x16_bf16(kf[c], qf[c], csw, 0, 0, 0);
        __builtin_amdgcn_s_setprio(0);

        // ---- reload K for next iter (post-consumption; ~1 iter of cover) ----
        if (i < st) {
            #pragma unroll
            for (int c = 0; c < 4; ++c)
                kf[c] = *(const short8*)(kfb + c * 16384 + (size_t)(t0 + 32) * 16);
        }

        // ---- gather RPE; mask only on the diagonal tile ----
        float sc[16];
        #pragma unroll
        for (int q = 0; q < 16; ++q) {
            const int trow = (q & 3) + 8 * (q >> 2) + 4 * hi;
            const int u = trow + 31 - sl;
            sc[q] = (csw[q] + bf2f(Mb[p][sl][u])) * 0.125f;
        }
        if (i == st) {
            #pragma unroll
            for (int q = 0; q < 16; ++q) {
                const int trow = (q & 3) + 8 * (q >> 2) + 4 * hi;
                if (t0 + trow > s0 + sl) sc[q] = -1e30f;
            }
        }
        // tree reduction for tmax (depth 4)
        float tm8[8], tm4[4];
        #pragma unroll
        for (int q = 0; q < 8; ++q) tm8[q] = fmaxf(sc[q], sc[q + 8]);
        #pragma unroll
        for (int q = 0; q < 4; ++q) tm4[q] = fmaxf(tm8[q], tm8[q + 4]);
        float tmax = fmaxf(fmaxf(tm4[0], tm4[1]), fmaxf(tm4[2], tm4[3]));

        // ---- DEFERRED skew GEMM for window i-1 (before rescale: exact) ----
        if (i > 0) {
            __builtin_amdgcn_s_setprio(1);
            #pragma unroll
            for (int c = 0; c < 4; ++c) {
                short8 pskew = *(const short8*)&Pb[p ^ 1][sl][16 * c + 8 * hi];
                acc0 = __builtin_amdgcn_mfma_f32_32x32x16_bf16(ea[c][0], pskew, acc0, 0, 0, 0);
                acc1 = __builtin_amdgcn_mfma_f32_32x32x16_bf16(ea[c][1], pskew, acc1, 0, 0, 0);
            }
            __builtin_amdgcn_s_setprio(0);
        }

        // ---- load ea for window i (used at next iter's skew / final skew) ----
        #pragma unroll
        for (int c = 0; c < 4; ++c)
            #pragma unroll
            for (int a = 0; a < 2; ++a)
                ea[c][a] = *(const short8*)(pevw + (size_t)(i + (c >> 1)) * 2048 +
                                            (c & 1) * 1024 + a * 512);

        // ---- online softmax with defer-max (THR=8) ----
        tmax = fmaxf(tmax, __shfl_xor(tmax, 32));
        if (!__all(tmax <= mrow + 8.f)) {
            const float mnew = fmaxf(mrow, tmax);
            const float r = __expf(mrow - mnew);
            lrow *= r;
            acc0 *= r; acc1 *= r;
            mrow = mnew;
        }
        float ps[16];
        #pragma unroll
        for (int q = 0; q < 16; ++q) ps[q] = __expf(sc[q] - mrow);
        // tree reduction for lsum (depth 4)
        float ls8[8], ls4[4];
        #pragma unroll
        for (int q = 0; q < 8; ++q) ls8[q] = ps[q] + ps[q + 8];
        #pragma unroll
        for (int q = 0; q < 4; ++q) ls4[q] = ls8[q] + ls8[q + 4];
        float lsum = (ls4[0] + ls4[1]) + (ls4[2] + ls4[3]);
        lsum += __shfl_xor(lsum, 32);
        lrow += lsum;

        // ---- write Pskew (bf16) into parity buffer p ----
        #pragma unroll
        for (int q = 0; q < 16; ++q) {
            const int trow = (q & 3) + 8 * (q >> 2) + 4 * hi;
            Pb[p][sl][trow + 31 - sl] = f2bf(ps[q]);
        }

        // ---- next M chunk (i+2) + pek prefetch for chunk i+3 ----
        if (i < st) {
            __builtin_amdgcn_s_setprio(1);
            mchunk(i + 2, 1, efn);
            __builtin_amdgcn_s_setprio(0);
            if (i + 1 < st) {
                #pragma unroll
                for (int c4 = 0; c4 < 4; ++c4)
                    efn[c4] = *(const short8*)(efb + (size_t)c4 * 32784 +
                                               (size_t)(RBASE + 32 * (i + 3)) * 16);
            }
        }

        // ---- PV: O^T += V^T · P^T ----
        float sh[16];
        #pragma unroll
        for (int q = 0; q < 16; ++q) sh[q] = __shfl_xor(ps[q], 32);
        __builtin_amdgcn_s_setprio(1);
        #pragma unroll
        for (int c = 0; c < 2; ++c) {
            short8 bfrag;
            #pragma unroll
            for (int j = 0; j < 8; ++j) {
                float pv;
                if (j < 4) pv = hi ? sh[8 * c + 4 + j] : ps[8 * c + j];
                else       pv = hi ? ps[8 * c + j]     : sh[8 * c + j - 4];
                bfrag[j] = (short)f2bf(pv);
            }
            acc0 = __builtin_amdgcn_mfma_f32_32x32x16_bf16(va[c][0], bfrag, acc0, 0, 0, 0);
            acc1 = __builtin_amdgcn_mfma_f32_32x32x16_bf16(va[c][1], bfrag, acc1, 0, 0, 0);
        }
        __builtin_amdgcn_s_setprio(0);

        // ---- reload V for next iter (post-consumption) ----
        if (i < st) {
            #pragma unroll
            for (int c = 0; c < 2; ++c)
                #pragma unroll
                for (int a = 0; a < 2; ++a)
                    va[c][a] = *(const short8*)(vfb + (size_t)(i + 1) * 2048 + (a * 2 + c) * 512);
        }
    }

    // ---- final skew GEMM for window st (ea loaded at iter st) ----
    {
        __builtin_amdgcn_s_setprio(1);
        #pragma unroll
        for (int c = 0; c < 4; ++c) {
            short8 pskew = *(const short8*)&Pb[st & 1][sl][16 * c + 8 * hi];
            acc0 = __builtin_amdgcn_mfma_f32_32x32x16_bf16(ea[c][0], pskew, acc0, 0, 0, 0);
            acc1 = __builtin_amdgcn_mfma_f32_32x32x16_bf16(ea[c][1], pskew, acc1, 0, 0, 0);
        }
        __builtin_amdgcn_s_setprio(0);
    }

    // ---- epilogue: bf16 packed stores ----
    const float inv = 1.0f / lrow;
    ushort* orow = AO + ((size_t)b * NS + s0 + sl) * NE + h * ND;
    #pragma unroll
    for (int g = 0; g < 4; ++g) {
        ushort4 o0 = make_ushort4(f2bf(acc0[4*g+0]*inv), f2bf(acc0[4*g+1]*inv),
                                  f2bf(acc0[4*g+2]*inv), f2bf(acc0[4*g+3]*inv));
        ushort4 o1 = make_ushort4(f2bf(acc1[4*g+0]*inv), f2bf(acc1[4*g+1]*inv),
                                  f2bf(acc1[4*g+2]*inv), f2bf(acc1[4*g+3]*inv));
        *(ushort4*)&orow[8 * g + 4 * hi]      = o0;
        *(ushort4*)&orow[8 * g + 4 * hi + 32] = o1;
    }
}

extern "C" void kernel_launch(void* const* d_in, const int* in_sizes, int n_in,
                              void* d_out, int out_size, void* d_ws, size_t ws_size,
                              hipStream_t stream) {
    const float* x   = (const float*)d_in[0];
    const float* Wq  = (const float*)d_in[2];
    const float* Wk  = (const float*)d_in[3];
    const float* Wv  = (const float*)d_in[4];
    const float* Wo  = (const float*)d_in[5];
    const float* pek = (const float*)d_in[6];
    const float* pev = (const float*)d_in[7];

    ushort* ws16 = (ushort*)d_ws;
    size_t off = 0;
    ushort* xb    = ws16 + off; off += (size_t)8388608;   // [8192,1024] bf16
    ushort* Wqb   = ws16 + off; off += (size_t)1048576;
    ushort* Wkb   = ws16 + off; off += (size_t)1048576;
    ushort* Wvb   = ws16 + off; off += (size_t)1048576;
    ushort* Wob   = ws16 + off; off += (size_t)1048576;
    ushort* Qb    = ws16 + off; off += (size_t)8388608;   // [B,H,S,D] row-major
    ushort* Kfm   = ws16 + off; off += (size_t)8388608;   // K fragment-major
    ushort* Vfm   = ws16 + off; off += (size_t)8388608;   // V fragment-major
    ushort* PEKf  = ws16 + off; off += (size_t)131136;    // pek fragment-major
    ushort* PEVf  = ws16 + off; off += (size_t)67584;     // pev fragment-major
    ushort* aob   = ws16 + off; off += (size_t)8388608;   // [B,S,E] bf16
    float*  out   = (float*)d_out;

    dim3 blk(256);
    cast_f2b4<<<8192, blk, 0, stream>>>(x, xb, 2097152);
    cast_w4<<<4096, blk, 0, stream>>>(Wq, Wk, Wv, Wo, Wqb);
    cast_pek<<<(2049 * 64 + 255) / 256, blk, 0, stream>>>(pek, PEKf, 2049 * 64);
    cast_pevt<<<(64 * 1056 + 255) / 256, blk, 0, stream>>>(pev, PEVf);

    gemm_mfma<0><<<dim3(64, 8), blk, 0, stream>>>(xb, Wqb, nullptr, Qb);
    gemm_mfma<4><<<dim3(64, 8), blk, 0, stream>>>(xb, Wkb, nullptr, Kfm);
    gemm_mfma<3><<<dim3(8, 64), blk, 0, stream>>>(Wvb, xb, nullptr, Vfm);

    attn_mfma<<<dim3(4096), dim3(64), 0, stream>>>(Qb, Kfm, Vfm, PEKf, PEVf, aob);

    gemm_mfma<1><<<dim3(64, 8), blk, 0, stream>>>(aob, Wob, out, nullptr);
}